// Round 14
// baseline (347.481 us; speedup 1.0000x reference)
//
#include <hip/hip_runtime.h>
#include <cstdint>

#define B_DIM 32
#define C_DIM 512
#define N_SP 1024
#define GROUPS 32
#define CPG 16
#define EPS 1e-5f

typedef __attribute__((ext_vector_type(8))) __bf16 bf16x8;
typedef __attribute__((ext_vector_type(4))) __bf16 bf16x4;
typedef __attribute__((ext_vector_type(4))) float f32x4;
typedef __attribute__((ext_vector_type(16))) float f32x16;

__device__ __forceinline__ void gload16(const void* g, void* l) {
    __builtin_amdgcn_global_load_lds(
        (__attribute__((address_space(1))) void*)(unsigned long long)(uintptr_t)g,
        (__attribute__((address_space(3))) void*)(unsigned int)(uintptr_t)l,
        16, 0, 0);
}

// ------- fused GroupNorm: stats + apply + transpose, one x read -------
__global__ __launch_bounds__(256) void gn_fused_kernel(const float* __restrict__ x,
                                                       const float* __restrict__ w,
                                                       const float* __restrict__ bia,
                                                       __bf16* __restrict__ hT) {
    __shared__ float tile[16][1025];
    __shared__ float sw[16], sb[16];
    __shared__ float ls[4], lq[4];
    const int bb = blockIdx.x >> 5, g = blockIdx.x & 31;
    const int t = threadIdx.x;
    const float* xb = x + ((size_t)(bb * C_DIM + g * CPG)) * N_SP;

    float s = 0.f, sq = 0.f;
#pragma unroll
    for (int i = 0; i < 16; ++i) {
        int idx = t + 256 * i;
        int row = idx >> 8, c4 = (idx & 255) * 4;
        float4 v = *(const float4*)&xb[(size_t)row * N_SP + c4];
        tile[row][c4 + 0] = v.x; tile[row][c4 + 1] = v.y;
        tile[row][c4 + 2] = v.z; tile[row][c4 + 3] = v.w;
        s  += v.x + v.y + v.z + v.w;
        sq += v.x * v.x + v.y * v.y + v.z * v.z + v.w * v.w;
    }
    for (int off = 32; off > 0; off >>= 1) {
        s  += __shfl_xor(s, off);
        sq += __shfl_xor(sq, off);
    }
    int wid = t >> 6;
    if ((t & 63) == 0) { ls[wid] = s; lq[wid] = sq; }
    __syncthreads();
    if (t < 16) {
        s  = ls[0] + ls[1] + ls[2] + ls[3];
        sq = lq[0] + lq[1] + lq[2] + lq[3];
        float mean = s / (float)(CPG * N_SP);
        float var  = sq / (float)(CPG * N_SP) - mean * mean;
        float rstd = rsqrtf(var + EPS);
        float scl = w[g * CPG + t] * rstd;
        sw[t] = scl;
        sb[t] = bia[g * CPG + t] - mean * scl;
    }
    __syncthreads();
    __bf16* hb = hT + ((size_t)bb * N_SP) * C_DIM + g * CPG;
#pragma unroll
    for (int i = 0; i < 4; ++i) {
        int n = t + 256 * i;
        bf16x8 o1, o2;
#pragma unroll
        for (int c = 0; c < 8; ++c) o1[c] = (__bf16)(tile[c][n] * sw[c] + sb[c]);
#pragma unroll
        for (int c = 0; c < 8; ++c) o2[c] = (__bf16)(tile[8 + c][n] * sw[8 + c] + sb[8 + c]);
        *(bf16x8*)&hb[(size_t)n * C_DIM] = o1;
        *(bf16x8*)&hb[(size_t)n * C_DIM + 8] = o2;
    }
}

// ------- prep: weights fp32->bf16 + pack qk bias -------
__global__ __launch_bounds__(256) void prep_kernel(const float* __restrict__ qw,
                                                   const float* __restrict__ kw,
                                                   const float* __restrict__ vw,
                                                   const float* __restrict__ pw,
                                                   const float* __restrict__ qb,
                                                   const float* __restrict__ kb,
                                                   __bf16* __restrict__ wqk,
                                                   __bf16* __restrict__ wv,
                                                   __bf16* __restrict__ wp,
                                                   float* __restrict__ qkb) {
    int bi = blockIdx.x;
    int t = threadIdx.x;
    if (bi == 1024) {
        int i = t * 4;
#pragma unroll
        for (int e = 0; e < 4; ++e)
            qkb[i + e] = (i + e < 512) ? qb[i + e] : kb[i + e - 512];
        return;
    }
    const float* src;
    __bf16* dst;
    int blk = bi & 255;
    if (bi < 256)       { src = qw; dst = wqk; }
    else if (bi < 512)  { src = kw; dst = wqk + 262144; }
    else if (bi < 768)  { src = vw; dst = wv; }
    else                { src = pw; dst = wp; }
    int i = blk * 256 + t;
    float4 v = ((const float4*)src)[i];
    bf16x4 o;
    o[0] = (__bf16)v.x; o[1] = (__bf16)v.y; o[2] = (__bf16)v.z; o[3] = (__bf16)v.w;
    ((bf16x4*)dst)[i] = o;
}

// ------- softmax: one wave per row of 1024 bf16, in place, no LDS -------
__global__ __launch_bounds__(256) void softmax_bf16(__bf16* __restrict__ S) {
    int row = blockIdx.x * 4 + (threadIdx.x >> 6);
    int lane = threadIdx.x & 63;
    __bf16* p = S + (size_t)row * N_SP + lane * 16;
    bf16x8 v0 = *(bf16x8*)p;
    bf16x8 v1 = *(bf16x8*)(p + 8);
    float f[16];
#pragma unroll
    for (int e = 0; e < 8; ++e) { f[e] = (float)v0[e]; f[8 + e] = (float)v1[e]; }
    float m = f[0];
#pragma unroll
    for (int e = 1; e < 16; ++e) m = fmaxf(m, f[e]);
    for (int off = 32; off > 0; off >>= 1) m = fmaxf(m, __shfl_xor(m, off));
    float s = 0.f;
#pragma unroll
    for (int e = 0; e < 16; ++e) { f[e] = __expf(f[e] - m); s += f[e]; }
    for (int off = 32; off > 0; off >>= 1) s += __shfl_xor(s, off);
    float inv = 1.f / s;
#pragma unroll
    for (int e = 0; e < 8; ++e) { v0[e] = (__bf16)(f[e] * inv); v1[e] = (__bf16)(f[8 + e] * inv); }
    *(bf16x8*)p = v0;
    *(bf16x8*)(p + 8) = v1;
}

// ==== 128x128 8-wave GEMM, BK=64, dbuf, depth-1.5 prefetch, 32x32x16 MFMA ====
// Same geometry/staging/swizzle as the verified r8 kernel; only the MFMA shape
// changes: per wave per K-tile 12 ds_read_b128 + 8 v_mfma_f32_32x32x16_bf16
// (vs 16 of 16x16x32) -> -17% matrix-pipe cycles (m119: 8.07cyc/32kFLOP).
// A/B frag: lane l -> row l&31, k = (l>>5)*8 + e (extension of the proven
// 16x16x32 mapping). C/D: col=lane&31, row=(reg&3)+8*(reg>>2)+4*(lane>>5).
// EPI: 0 bf16; 2 bf16+bias[row]; 4 f32+bias[row]+resid (prefetched tail);
//      5 bf16*scale; 6 bf16+bias[col] split cols<512 -> Y, >=512 -> Y2
#define WAITV(n) asm volatile("s_waitcnt vmcnt(" #n ")" ::: "memory")
#define BAR() __builtin_amdgcn_s_barrier()

template <int M, int N, int K, int LDA, int LDB, int EPI>
__global__ __launch_bounds__(512, 4) void gemmP(const __bf16* __restrict__ A, size_t sA,
                                                const __bf16* __restrict__ BT, size_t sB,
                                                void* __restrict__ Y, size_t sY,
                                                const float* __restrict__ bias,
                                                const float* __restrict__ resid, size_t sR,
                                                float scale, void* __restrict__ Y2) {
    static_assert(M % 128 == 0 && N % 128 == 0 && K % 128 == 0, "shape");
    constexpr int GX = N / 128, GY = M / 128, NT = K / 64;
    __shared__ __align__(16) __bf16 lds[2][2][8192];   // [buf][A/B][128 rows x 64 k]

    const int tid = threadIdx.x;
    const int w = tid >> 6, lane = tid & 63;
    const int wm = w >> 1, wn = w & 1;                 // 4 x 2 wave grid, tile 32x64
    const int l31 = lane & 31, khalf = lane >> 5;
    const int l7 = l31 & 7;

    const int nwg = gridDim.x;
    const int wg = ((int)blockIdx.x & 7) * (nwg >> 3) + ((int)blockIdx.x >> 3);
    const int bz = wg / (GX * GY);
    const int rem = wg - bz * (GX * GY);
    const int bm = (rem / GX) * 128, bn = (rem % GX) * 128;

    const __bf16* Ab = A + (size_t)bz * sA;
    const __bf16* Bb = BT + (size_t)bz * sB;

    const int srow = tid >> 3;
    const int kswz = ((tid & 7) ^ (srow & 7)) * 8;
    const __bf16* srcA = Ab + (size_t)(bm + srow) * LDA + kswz;
    const __bf16* srcB = Bb + (size_t)(bn + srow) * LDB + kswz;

#define STG(buf, kt) do { \
    gload16(srcA + (size_t)(kt) * 64,                      &lds[buf][0][w * 512]); \
    gload16(srcA + (size_t)64 * LDA + (size_t)(kt) * 64,   &lds[buf][0][4096 + w * 512]); \
    gload16(srcB + (size_t)(kt) * 64,                      &lds[buf][1][w * 512]); \
    gload16(srcB + (size_t)64 * LDB + (size_t)(kt) * 64,   &lds[buf][1][4096 + w * 512]); \
} while (0)

    // fragment reads: LDS[row][slot] holds global k-slot (slot ^ (row&7));
    // lane wants k-slot (2s+khalf) for kstep s -> LDS slot = (2s+khalf)^(row&7)
    const int arow  = (wm * 32 + l31) * 64;
    const int brow0 = (wn * 64 + l31) * 64;
    const int brow1 = (wn * 64 + 32 + l31) * 64;
    int ksl[4];
#pragma unroll
    for (int s = 0; s < 4; ++s) ksl[s] = ((2 * s + khalf) ^ l7) * 8;

    bf16x8 aF[4], bF[4][2];
    f32x16 acc[2];
#pragma unroll
    for (int j = 0; j < 2; ++j)
#pragma unroll
        for (int r = 0; r < 16; ++r) acc[j][r] = 0.f;

    const float* Rb = (EPI == 4) ? (resid + (size_t)bz * sR) : nullptr;
    float xr[2][16];   // EPI==4 residual prefetch (DCE'd otherwise)

#define RD_ALL(ct) do { \
    _Pragma("unroll") for (int s = 0; s < 4; ++s) { \
        aF[s]    = *(const bf16x8*)&lds[ct][0][arow  + ksl[s]]; \
        bF[s][0] = *(const bf16x8*)&lds[ct][1][brow0 + ksl[s]]; \
        bF[s][1] = *(const bf16x8*)&lds[ct][1][brow1 + ksl[s]]; } \
} while (0)

#define MMH(S0) do { \
    __builtin_amdgcn_s_setprio(1); \
    _Pragma("unroll") for (int s = (S0); s < (S0) + 2; ++s) \
    _Pragma("unroll") for (int j = 0; j < 2; ++j) \
        acc[j] = __builtin_amdgcn_mfma_f32_32x32x16_bf16( \
            aF[s], bF[s][j], acc[j], 0, 0, 0); \
    __builtin_amdgcn_s_setprio(0); \
} while (0)

    STG(0, 0);
    STG(1, 1);

#pragma unroll 1
    for (int t = 0; t < NT; ++t) {
        const int c = t & 1;
        if (t < NT - 1) { WAITV(4); } else { WAITV(0); }
        BAR();
        if constexpr (EPI == 4) {
            if (t == NT - 1) {     // residual prefetch flies under tail MFMAs
#pragma unroll
                for (int reg = 0; reg < 16; ++reg) {
                    int grow = bm + wm * 32 + (reg & 3) + 8 * (reg >> 2) + 4 * khalf;
#pragma unroll
                    for (int j = 0; j < 2; ++j)
                        xr[j][reg] = Rb[(size_t)grow * N + bn + wn * 64 + j * 32 + l31];
                }
            }
        }
        RD_ALL(c);                 // 12 x ds_read_b128
        MMH(0);                    // ksteps 0-1 (4 MFMA)
        asm volatile("s_waitcnt lgkmcnt(0)" ::: "memory");
        __builtin_amdgcn_sched_barrier(0);
        BAR();                     // all waves done reading buf c
        if (t + 2 < NT) STG(c, t + 2);
        MMH(2);                    // ksteps 2-3 (4 MFMA) cover the stage issue
    }

    // epilogue: C/D layout col=lane&31, row=(reg&3)+8*(reg>>2)+4*(lane>>5)
    float* Yf = (float*)Y + (size_t)bz * sY;
    __bf16* Yh = (__bf16*)Y + (size_t)bz * sY;
    __bf16* Y6 = (EPI == 6) ? ((bn < 512) ? (__bf16*)Y : (__bf16*)Y2) : nullptr;
#pragma unroll
    for (int reg = 0; reg < 16; ++reg) {
        int grow = bm + wm * 32 + (reg & 3) + 8 * (reg >> 2) + 4 * khalf;
        float brv = (EPI == 2 || EPI == 4) ? bias[grow] : 0.f;
#pragma unroll
        for (int j = 0; j < 2; ++j) {
            int gcol = bn + wn * 64 + j * 32 + l31;
            float vv = acc[j][reg];
            if (EPI == 6) vv += bias[gcol];
            if (EPI == 2 || EPI == 4) vv += brv;
            if (EPI == 5) vv *= scale;
            if (EPI == 4) {
                Yf[(size_t)grow * N + gcol] = vv + xr[j][reg];
            } else if (EPI == 6) {
                Y6[(size_t)grow * 512 + (gcol & 511)] = (__bf16)vv;
            } else {
                Yh[(size_t)grow * N + gcol] = (__bf16)vv;
            }
        }
    }
#undef STG
#undef RD_ALL
#undef MMH
}

extern "C" void kernel_launch(void* const* d_in, const int* in_sizes, int n_in,
                              void* d_out, int out_size, void* d_ws, size_t ws_size,
                              hipStream_t stream) {
    const float* x      = (const float*)d_in[0];
    const float* norm_w = (const float*)d_in[1];
    const float* norm_b = (const float*)d_in[2];
    const float* q_w    = (const float*)d_in[3];
    const float* q_b    = (const float*)d_in[4];
    const float* k_w    = (const float*)d_in[5];
    const float* k_b    = (const float*)d_in[6];
    const float* v_w    = (const float*)d_in[7];
    const float* v_b    = (const float*)d_in[8];
    const float* proj_w = (const float*)d_in[9];
    const float* proj_b = (const float*)d_in[10];
    float* out = (float*)d_out;

    const size_t ELEM = (size_t)N_SP * C_DIM;            // 524288 elems = 1MB bf16
    const size_t QK   = (size_t)N_SP * N_SP;
    char* ws = (char*)d_ws;
    __bf16* hT  = (__bf16*)ws;                           // 32MB [b][n][c], reused as Ot
    __bf16* qT  = (__bf16*)(ws + ((size_t)32 << 20));    // 32MB [b][n][512]
    __bf16* kT  = (__bf16*)(ws + ((size_t)64 << 20));    // 32MB [b][n][512]
    __bf16* wqk = (__bf16*)(ws + ((size_t)96 << 20));    // 1MB [1024][512]
    __bf16* wv  = (__bf16*)(ws + ((size_t)97 << 20));    // 0.5MB
    __bf16* wp  = wv + 262144;                           // 0.5MB
    float* qkb  = (float*)(ws + ((size_t)98 << 20));     // 4KB
    size_t sbase = ((size_t)99 << 20);
    __bf16* S = (__bf16*)(ws + sbase);                   // chunk x [1024][1024] bf16
    __bf16* v  = (__bf16*)d_out;                         // V lives in d_out until proj
    __bf16* Ot = hT;

    int chunk = (int)((ws_size - sbase) >> 21);          // 2MB per batch of S
    if (chunk > B_DIM) chunk = B_DIM;
    if (chunk < 1) chunk = 1;

    gn_fused_kernel<<<B_DIM * GROUPS, 256, 0, stream>>>(x, norm_w, norm_b, hT);
    prep_kernel<<<1025, 256, 0, stream>>>(q_w, k_w, v_w, proj_w, q_b, k_b,
                                          wqk, wv, wp, qkb);

    // qT[n][oc] / kT[n][oc] = hT[n][:] x (wq||wk)^T + bias, split outputs
    gemmP<32768, 1024, 512, 512, 512, 6><<<2048, 512, 0, stream>>>(
        hT, 0, wqk, 0, qT, 0, qkb, nullptr, 0, 1.f, kT);
    // v[b][oc][n] = wv[oc][:] x hT[b][n][:] + v_b[oc]
    gemmP<512, 1024, 512, 512, 512, 2><<<1024, 512, 0, stream>>>(
        wv, 0, hT, ELEM, v, ELEM, v_b, nullptr, 0, 1.f, nullptr);

    const float scale = 0.044194173824159216f;  // 512^-0.5
    for (int b0 = 0; b0 < B_DIM; b0 += chunk) {
        int nb = (b0 + chunk <= B_DIM) ? chunk : (B_DIM - b0);
        // S[i][j] = bf16( scale * sum_c qT[i][c] kT[j][c] )
        gemmP<1024, 1024, 512, 512, 512, 5><<<64 * nb, 512, 0, stream>>>(
            qT + (size_t)b0 * ELEM, ELEM, kT + (size_t)b0 * ELEM, ELEM,
            S, QK, nullptr, nullptr, 0, scale, nullptr);
        softmax_bf16<<<nb * N_SP / 4, 256, 0, stream>>>(S);
        // Ot[i][c] = sum_j P[i][j] v[c][j]
        gemmP<1024, 512, 1024, 1024, 1024, 0><<<32 * nb, 512, 0, stream>>>(
            S, QK, v + (size_t)b0 * ELEM, ELEM,
            Ot + (size_t)b0 * ELEM, ELEM, nullptr, nullptr, 0, 1.f, nullptr);
    }

    // out[b][oc][n] = wp[oc][:] x Ot[b][n][:] + proj_b[oc] + x[b][oc][n]
    gemmP<512, 1024, 512, 512, 512, 4><<<1024, 512, 0, stream>>>(
        wp, 0, Ot, ELEM, out, ELEM, proj_b, x, ELEM, 1.f, nullptr);
}

// Round 15
// 305.071 us; speedup vs baseline: 1.1390x; 1.1390x over previous
//
#include <hip/hip_runtime.h>
#include <cstdint>

#define B_DIM 32
#define C_DIM 512
#define N_SP 1024
#define GROUPS 32
#define CPG 16
#define EPS 1e-5f

typedef __attribute__((ext_vector_type(8))) __bf16 bf16x8;
typedef __attribute__((ext_vector_type(4))) __bf16 bf16x4;
typedef __attribute__((ext_vector_type(4))) float f32x4;

__device__ __forceinline__ void gload16(const void* g, void* l) {
    __builtin_amdgcn_global_load_lds(
        (__attribute__((address_space(1))) void*)(unsigned long long)(uintptr_t)g,
        (__attribute__((address_space(3))) void*)(unsigned int)(uintptr_t)l,
        16, 0, 0);
}

// ------- fused GroupNorm: stats + apply + transpose, one x read -------
__global__ __launch_bounds__(256) void gn_fused_kernel(const float* __restrict__ x,
                                                       const float* __restrict__ w,
                                                       const float* __restrict__ bia,
                                                       __bf16* __restrict__ hT) {
    __shared__ float tile[16][1025];
    __shared__ float sw[16], sb[16];
    __shared__ float ls[4], lq[4];
    const int bb = blockIdx.x >> 5, g = blockIdx.x & 31;
    const int t = threadIdx.x;
    const float* xb = x + ((size_t)(bb * C_DIM + g * CPG)) * N_SP;

    float s = 0.f, sq = 0.f;
#pragma unroll
    for (int i = 0; i < 16; ++i) {
        int idx = t + 256 * i;
        int row = idx >> 8, c4 = (idx & 255) * 4;
        float4 v = *(const float4*)&xb[(size_t)row * N_SP + c4];
        tile[row][c4 + 0] = v.x; tile[row][c4 + 1] = v.y;
        tile[row][c4 + 2] = v.z; tile[row][c4 + 3] = v.w;
        s  += v.x + v.y + v.z + v.w;
        sq += v.x * v.x + v.y * v.y + v.z * v.z + v.w * v.w;
    }
    for (int off = 32; off > 0; off >>= 1) {
        s  += __shfl_xor(s, off);
        sq += __shfl_xor(sq, off);
    }
    int wid = t >> 6;
    if ((t & 63) == 0) { ls[wid] = s; lq[wid] = sq; }
    __syncthreads();
    if (t < 16) {
        s  = ls[0] + ls[1] + ls[2] + ls[3];
        sq = lq[0] + lq[1] + lq[2] + lq[3];
        float mean = s / (float)(CPG * N_SP);
        float var  = sq / (float)(CPG * N_SP) - mean * mean;
        float rstd = rsqrtf(var + EPS);
        float scl = w[g * CPG + t] * rstd;
        sw[t] = scl;
        sb[t] = bia[g * CPG + t] - mean * scl;
    }
    __syncthreads();
    __bf16* hb = hT + ((size_t)bb * N_SP) * C_DIM + g * CPG;
#pragma unroll
    for (int i = 0; i < 4; ++i) {
        int n = t + 256 * i;
        bf16x8 o1, o2;
#pragma unroll
        for (int c = 0; c < 8; ++c) o1[c] = (__bf16)(tile[c][n] * sw[c] + sb[c]);
#pragma unroll
        for (int c = 0; c < 8; ++c) o2[c] = (__bf16)(tile[8 + c][n] * sw[8 + c] + sb[8 + c]);
        *(bf16x8*)&hb[(size_t)n * C_DIM] = o1;
        *(bf16x8*)&hb[(size_t)n * C_DIM + 8] = o2;
    }
}

// ------- wv transpose + bf16: wvT[in][out] = v_w[out][in] -------
__global__ __launch_bounds__(256) void wvt_kernel(const float* __restrict__ vw,
                                                  __bf16* __restrict__ wvT) {
    __shared__ float t[64][65];
    const int br = blockIdx.y * 64;    // rows of vw (out-ch)
    const int bc = blockIdx.x * 64;    // cols of vw (in-ch)
    const int tid = threadIdx.x;
#pragma unroll
    for (int it = 0; it < 4; ++it) {
        int r = (tid >> 4) + 16 * it;
        int c4 = (tid & 15) * 4;
        float4 v = *(const float4*)&vw[(size_t)(br + r) * 512 + bc + c4];
        t[r][c4 + 0] = v.x; t[r][c4 + 1] = v.y;
        t[r][c4 + 2] = v.z; t[r][c4 + 3] = v.w;
    }
    __syncthreads();
    int rr = tid >> 2, cc = (tid & 3) * 16;
    bf16x8 o1, o2;
#pragma unroll
    for (int e = 0; e < 8; ++e) o1[e] = (__bf16)t[cc + e][rr];
#pragma unroll
    for (int e = 0; e < 8; ++e) o2[e] = (__bf16)t[cc + 8 + e][rr];
    __bf16* dst = &wvT[(size_t)(bc + rr) * 512 + br + cc];
    *(bf16x8*)dst = o1;
    *(bf16x8*)(dst + 8) = o2;
}

// ------- prep: q/k/proj weights fp32->bf16, pack qk bias, b2 = wp.v_b -------
__global__ __launch_bounds__(256) void prep_kernel(const float* __restrict__ qw,
                                                   const float* __restrict__ kw,
                                                   const float* __restrict__ pw,
                                                   const float* __restrict__ qb,
                                                   const float* __restrict__ kb,
                                                   const float* __restrict__ vb,
                                                   __bf16* __restrict__ wqk,
                                                   __bf16* __restrict__ wp,
                                                   float* __restrict__ qkb,
                                                   float* __restrict__ b2) {
    int bi = blockIdx.x;
    int t = threadIdx.x;
    if (bi == 768) {
        int i = t * 4;
#pragma unroll
        for (int e = 0; e < 4; ++e)
            qkb[i + e] = (i + e < 512) ? qb[i + e] : kb[i + e - 512];
        return;
    }
    if (bi == 769) {
#pragma unroll 1
        for (int rep = 0; rep < 2; ++rep) {
            int o = t + 256 * rep;
            float s = 0.f;
            for (int m = 0; m < 512; ++m) s += pw[(size_t)o * 512 + m] * vb[m];
            b2[o] = s;
        }
        return;
    }
    const float* src;
    __bf16* dst;
    int blk = bi & 255;
    if (bi < 256)       { src = qw; dst = wqk; }
    else if (bi < 512)  { src = kw; dst = wqk + 262144; }
    else                { src = pw; dst = wp; }
    int i = blk * 256 + t;
    float4 v = ((const float4*)src)[i];
    bf16x4 o;
    o[0] = (__bf16)v.x; o[1] = (__bf16)v.y; o[2] = (__bf16)v.z; o[3] = (__bf16)v.w;
    ((bf16x4*)dst)[i] = o;
}

// ------- softmax: one wave per row of 1024 bf16, in place, no LDS -------
__global__ __launch_bounds__(256) void softmax_bf16(__bf16* __restrict__ S) {
    int row = blockIdx.x * 4 + (threadIdx.x >> 6);
    int lane = threadIdx.x & 63;
    __bf16* p = S + (size_t)row * N_SP + lane * 16;
    bf16x8 v0 = *(bf16x8*)p;
    bf16x8 v1 = *(bf16x8*)(p + 8);
    float f[16];
#pragma unroll
    for (int e = 0; e < 8; ++e) { f[e] = (float)v0[e]; f[8 + e] = (float)v1[e]; }
    float m = f[0];
#pragma unroll
    for (int e = 1; e < 16; ++e) m = fmaxf(m, f[e]);
    for (int off = 32; off > 0; off >>= 1) m = fmaxf(m, __shfl_xor(m, off));
    float s = 0.f;
#pragma unroll
    for (int e = 0; e < 16; ++e) { f[e] = __expf(f[e] - m); s += f[e]; }
    for (int off = 32; off > 0; off >>= 1) s += __shfl_xor(s, off);
    float inv = 1.f / s;
#pragma unroll
    for (int e = 0; e < 8; ++e) { v0[e] = (__bf16)(f[e] * inv); v1[e] = (__bf16)(f[8 + e] * inv); }
    *(bf16x8*)p = v0;
    *(bf16x8*)(p + 8) = v1;
}

// ============ 128x128 8-wave GEMM, BK=64, dbuf, depth-1.5 prefetch ============
// (verbatim r8 kernel — 247us best config)
// EPI: 0 bf16; 2 bf16+bias[row]; 4 f32+bias[row]+resid (resid prefetched tail);
//      5 bf16*scale; 6 bf16+bias[col] split cols<512 -> Y, >=512 -> Y2
#define WAITV(n) asm volatile("s_waitcnt vmcnt(" #n ")" ::: "memory")
#define BAR() __builtin_amdgcn_s_barrier()

template <int M, int N, int K, int LDA, int LDB, int EPI>
__global__ __launch_bounds__(512, 4) void gemmP(const __bf16* __restrict__ A, size_t sA,
                                                const __bf16* __restrict__ BT, size_t sB,
                                                void* __restrict__ Y, size_t sY,
                                                const float* __restrict__ bias,
                                                const float* __restrict__ resid, size_t sR,
                                                float scale, void* __restrict__ Y2) {
    static_assert(M % 128 == 0 && N % 128 == 0 && K % 128 == 0, "shape");
    constexpr int GX = N / 128, GY = M / 128, NT = K / 64;
    __shared__ __align__(16) __bf16 lds[2][2][8192];   // [buf][A/B][128 rows x 64 k]

    const int tid = threadIdx.x;
    const int w = tid >> 6, lane = tid & 63;
    const int wm = w >> 1, wn = w & 1;                 // 4 x 2 wave grid, tile 32x64
    const int lrow = lane & 15, koct = lane >> 4;

    const int nwg = gridDim.x;
    const int wg = ((int)blockIdx.x & 7) * (nwg >> 3) + ((int)blockIdx.x >> 3);
    const int bz = wg / (GX * GY);
    const int rem = wg - bz * (GX * GY);
    const int bm = (rem / GX) * 128, bn = (rem % GX) * 128;

    const __bf16* Ab = A + (size_t)bz * sA;
    const __bf16* Bb = BT + (size_t)bz * sB;

    const int srow = tid >> 3;
    const int kswz = ((tid & 7) ^ (srow & 7)) * 8;
    const __bf16* srcA = Ab + (size_t)(bm + srow) * LDA + kswz;
    const __bf16* srcB = Bb + (size_t)(bn + srow) * LDB + kswz;

#define STG(buf, kt) do { \
    gload16(srcA + (size_t)(kt) * 64,                      &lds[buf][0][w * 512]); \
    gload16(srcA + (size_t)64 * LDA + (size_t)(kt) * 64,   &lds[buf][0][4096 + w * 512]); \
    gload16(srcB + (size_t)(kt) * 64,                      &lds[buf][1][w * 512]); \
    gload16(srcB + (size_t)64 * LDB + (size_t)(kt) * 64,   &lds[buf][1][4096 + w * 512]); \
} while (0)

    const int ks0 = (koct ^ (lrow & 7)) * 8;
    const int ks1 = ks0 ^ 32;
    const int aoff = (wm * 32 + lrow) * 64;
    const int boff = (wn * 64 + lrow) * 64;

    bf16x8 aF[2][2], bF[4][2];
    f32x4 acc[2][4];
#pragma unroll
    for (int i = 0; i < 2; ++i)
#pragma unroll
        for (int j = 0; j < 4; ++j) acc[i][j] = (f32x4){0.f, 0.f, 0.f, 0.f};

    const float* Rb = (EPI == 4) ? (resid + (size_t)bz * sR) : nullptr;
    float xr[2][4][4];   // EPI==4 residual prefetch (DCE'd otherwise)

#define RD_ALL(ct) do { \
    _Pragma("unroll") for (int i = 0; i < 2; ++i) { \
        aF[i][0] = *(const bf16x8*)&lds[ct][0][aoff + i * 1024 + ks0]; \
        aF[i][1] = *(const bf16x8*)&lds[ct][0][aoff + i * 1024 + ks1]; } \
    _Pragma("unroll") for (int j = 0; j < 4; ++j) { \
        bF[j][0] = *(const bf16x8*)&lds[ct][1][boff + j * 1024 + ks0]; \
        bF[j][1] = *(const bf16x8*)&lds[ct][1][boff + j * 1024 + ks1]; } \
} while (0)

#define MM8(KS) do { \
    __builtin_amdgcn_s_setprio(1); \
    _Pragma("unroll") for (int i = 0; i < 2; ++i) \
    _Pragma("unroll") for (int j = 0; j < 4; ++j) \
        acc[i][j] = __builtin_amdgcn_mfma_f32_16x16x32_bf16( \
            aF[i][KS], bF[j][KS], acc[i][j], 0, 0, 0); \
    __builtin_amdgcn_s_setprio(0); \
} while (0)

    STG(0, 0);
    STG(1, 1);

#pragma unroll 1
    for (int t = 0; t < NT; ++t) {
        const int c = t & 1;
        if (t < NT - 1) { WAITV(4); } else { WAITV(0); }
        BAR();
        if constexpr (EPI == 4) {
            if (t == NT - 1) {     // residual prefetch flies under tail MFMAs
#pragma unroll
                for (int i = 0; i < 2; ++i)
#pragma unroll
                    for (int r = 0; r < 4; ++r)
#pragma unroll
                        for (int j = 0; j < 4; ++j)
                            xr[i][r][j] = Rb[(size_t)(bm + wm * 32 + i * 16 + koct * 4 + r) * N
                                             + bn + wn * 64 + j * 16 + lrow];
            }
        }
        RD_ALL(c);
        MM8(0);
        asm volatile("s_waitcnt lgkmcnt(0)" ::: "memory");
        __builtin_amdgcn_sched_barrier(0);
        BAR();
        if (t + 2 < NT) STG(c, t + 2);
        MM8(1);
    }

    // epilogue: C/D layout col=lane&15, row=koct*4+reg
    float* Yf = (float*)Y + (size_t)bz * sY;
    __bf16* Yh = (__bf16*)Y + (size_t)bz * sY;
    __bf16* Y6 = (EPI == 6) ? ((bn < 512) ? (__bf16*)Y : (__bf16*)Y2) : nullptr;
#pragma unroll
    for (int i = 0; i < 2; ++i)
#pragma unroll
        for (int r = 0; r < 4; ++r) {
            int grow = bm + wm * 32 + i * 16 + koct * 4 + r;
            float brv = (EPI == 2 || EPI == 4) ? bias[grow] : 0.f;
#pragma unroll
            for (int j = 0; j < 4; ++j) {
                int gcol = bn + wn * 64 + j * 16 + lrow;
                float vv = acc[i][j][r];
                if (EPI == 6) vv += bias[gcol];
                if (EPI == 2 || EPI == 4) vv += brv;
                if (EPI == 5) vv *= scale;
                if (EPI == 4) {
                    Yf[(size_t)grow * N + gcol] = vv + xr[i][r][j];
                } else if (EPI == 6) {
                    Y6[(size_t)grow * 512 + (gcol & 511)] = (__bf16)vv;
                } else {
                    Yh[(size_t)grow * N + gcol] = (__bf16)vv;
                }
            }
        }
#undef STG
#undef RD_ALL
#undef MM8
}

extern "C" void kernel_launch(void* const* d_in, const int* in_sizes, int n_in,
                              void* d_out, int out_size, void* d_ws, size_t ws_size,
                              hipStream_t stream) {
    const float* x      = (const float*)d_in[0];
    const float* norm_w = (const float*)d_in[1];
    const float* norm_b = (const float*)d_in[2];
    const float* q_w    = (const float*)d_in[3];
    const float* q_b    = (const float*)d_in[4];
    const float* k_w    = (const float*)d_in[5];
    const float* k_b    = (const float*)d_in[6];
    const float* v_w    = (const float*)d_in[7];
    const float* v_b    = (const float*)d_in[8];
    const float* proj_w = (const float*)d_in[9];
    const float* proj_b = (const float*)d_in[10];
    float* out = (float*)d_out;

    const size_t ELEM = (size_t)N_SP * C_DIM;            // 524288 elems
    const size_t QK   = (size_t)N_SP * N_SP;
    char* ws = (char*)d_ws;
    __bf16* hT  = (__bf16*)ws;                           // 32MB [b][n][c]
    __bf16* qT  = (__bf16*)(ws + ((size_t)32 << 20));    // 32MB [b][n][512]
    __bf16* kT  = (__bf16*)(ws + ((size_t)64 << 20));    // 32MB [b][n][512]
    __bf16* wqk = (__bf16*)(ws + ((size_t)96 << 20));    // 1MB [1024][512]
    __bf16* wvT = (__bf16*)(ws + ((size_t)97 << 20));    // 0.5MB (v_w transposed)
    __bf16* wp  = wvT + 262144;                          // 0.5MB
    __bf16* W2  = (__bf16*)(ws + ((size_t)98 << 20));    // 0.5MB = wp.wv
    float* qkb  = (float*)(ws + ((size_t)98 << 20) + (512 << 10));  // 4KB
    float* b2   = qkb + 1024;                            // 2KB = wp.v_b
    size_t sbase = ((size_t)99 << 20);
    __bf16* S  = (__bf16*)(ws + sbase);                  // 64MB: 32 x [1024][1024] bf16
    __bf16* VP = (__bf16*)(ws + sbase + ((size_t)64 << 20));  // 32MB [b][oc][n]

    int chunk = (int)((ws_size > sbase + ((size_t)96 << 20))
                      ? 32 : ((ws_size - sbase - ((size_t)32 << 20)) >> 21));
    if (chunk > B_DIM) chunk = B_DIM;
    if (chunk < 1) chunk = 1;

    gn_fused_kernel<<<B_DIM * GROUPS, 256, 0, stream>>>(x, norm_w, norm_b, hT);
    wvt_kernel<<<dim3(8, 8), 256, 0, stream>>>(v_w, wvT);
    prep_kernel<<<770, 256, 0, stream>>>(q_w, k_w, proj_w, q_b, k_b, v_b,
                                         wqk, wp, qkb, b2);

    // W2[o][m] = sum_c wp[o][c] * wv[c][m]   (= wp . wvT^T)
    gemmP<512, 512, 512, 512, 512, 0><<<16, 512, 0, stream>>>(
        wp, 0, wvT, 0, W2, 0, nullptr, nullptr, 0, 1.f, nullptr);

    // qT[n][oc] / kT[n][oc] = hT[n][:] x (wq||wk)^T + bias, split outputs
    gemmP<32768, 1024, 512, 512, 512, 6><<<2048, 512, 0, stream>>>(
        hT, 0, wqk, 0, qT, 0, qkb, nullptr, 0, 1.f, kT);

    // VP[b][o][n] = W2[o][:] . hT[b][n][:] + b2[o]
    gemmP<512, 1024, 512, 512, 512, 2><<<1024, 512, 0, stream>>>(
        W2, 0, hT, ELEM, VP, ELEM, b2, nullptr, 0, 1.f, nullptr);

    const float scale = 0.044194173824159216f;  // 512^-0.5
    for (int b0 = 0; b0 < B_DIM; b0 += chunk) {
        int nb = (b0 + chunk <= B_DIM) ? chunk : (B_DIM - b0);
        // S[i][j] = bf16( scale * sum_c qT[i][c] kT[j][c] )
        gemmP<1024, 1024, 512, 512, 512, 5><<<64 * nb, 512, 0, stream>>>(
            qT + (size_t)b0 * ELEM, ELEM, kT + (size_t)b0 * ELEM, ELEM,
            S, QK, nullptr, nullptr, 0, scale, nullptr);
        softmax_bf16<<<nb * N_SP / 4, 256, 0, stream>>>(S);
        // out[b][o][i] = sum_j VP[o][j] P[i][j] + proj_b[o] + x[b][o][i]
        gemmP<512, 1024, 1024, 1024, 1024, 4><<<32 * nb, 512, 0, stream>>>(
            VP + (size_t)b0 * ELEM, ELEM, S, QK,
            out + (size_t)b0 * ELEM, ELEM, proj_b,
            x + (size_t)b0 * ELEM, ELEM, 1.f, nullptr);
    }
}

// Round 16
// 285.490 us; speedup vs baseline: 1.2171x; 1.0686x over previous
//
#include <hip/hip_runtime.h>
#include <cstdint>

#define B_DIM 32
#define C_DIM 512
#define N_SP 1024
#define GROUPS 32
#define CPG 16
#define EPS 1e-5f

typedef __attribute__((ext_vector_type(8))) __bf16 bf16x8;
typedef __attribute__((ext_vector_type(4))) __bf16 bf16x4;
typedef __attribute__((ext_vector_type(4))) float f32x4;

__device__ __forceinline__ void gload16(const void* g, void* l) {
    __builtin_amdgcn_global_load_lds(
        (__attribute__((address_space(1))) void*)(unsigned long long)(uintptr_t)g,
        (__attribute__((address_space(3))) void*)(unsigned int)(uintptr_t)l,
        16, 0, 0);
}

// ------- fused GroupNorm: stats + apply + transpose, one x read -------
// one block per (b,g): 16 ch x 1024. x[b][c][n] -> hT[b][n][c] bf16.
__global__ __launch_bounds__(256) void gn_fused_kernel(const float* __restrict__ x,
                                                       const float* __restrict__ w,
                                                       const float* __restrict__ bia,
                                                       __bf16* __restrict__ hT) {
    __shared__ float tile[16][1025];
    __shared__ float sw[16], sb[16];
    __shared__ float ls[4], lq[4];
    const int bb = blockIdx.x >> 5, g = blockIdx.x & 31;
    const int t = threadIdx.x;
    const float* xb = x + ((size_t)(bb * C_DIM + g * CPG)) * N_SP;

    float s = 0.f, sq = 0.f;
#pragma unroll
    for (int i = 0; i < 16; ++i) {
        int idx = t + 256 * i;            // 0..4095 float4s
        int row = idx >> 8, c4 = (idx & 255) * 4;
        float4 v = *(const float4*)&xb[(size_t)row * N_SP + c4];
        tile[row][c4 + 0] = v.x; tile[row][c4 + 1] = v.y;
        tile[row][c4 + 2] = v.z; tile[row][c4 + 3] = v.w;
        s  += v.x + v.y + v.z + v.w;
        sq += v.x * v.x + v.y * v.y + v.z * v.z + v.w * v.w;
    }
    for (int off = 32; off > 0; off >>= 1) {
        s  += __shfl_xor(s, off);
        sq += __shfl_xor(sq, off);
    }
    int wid = t >> 6;
    if ((t & 63) == 0) { ls[wid] = s; lq[wid] = sq; }
    __syncthreads();
    if (t < 16) {
        s  = ls[0] + ls[1] + ls[2] + ls[3];
        sq = lq[0] + lq[1] + lq[2] + lq[3];
        float mean = s / (float)(CPG * N_SP);
        float var  = sq / (float)(CPG * N_SP) - mean * mean;
        float rstd = rsqrtf(var + EPS);
        float scl = w[g * CPG + t] * rstd;
        sw[t] = scl;
        sb[t] = bia[g * CPG + t] - mean * scl;
    }
    __syncthreads();
    __bf16* hb = hT + ((size_t)bb * N_SP) * C_DIM + g * CPG;
#pragma unroll
    for (int i = 0; i < 4; ++i) {
        int n = t + 256 * i;
        bf16x8 o1, o2;
#pragma unroll
        for (int c = 0; c < 8; ++c) o1[c] = (__bf16)(tile[c][n] * sw[c] + sb[c]);
#pragma unroll
        for (int c = 0; c < 8; ++c) o2[c] = (__bf16)(tile[8 + c][n] * sw[8 + c] + sb[8 + c]);
        *(bf16x8*)&hb[(size_t)n * C_DIM] = o1;
        *(bf16x8*)&hb[(size_t)n * C_DIM + 8] = o2;
    }
}

// ------- fused prep: convert 4 weight matrices fp32->bf16 + pack qk bias -------
__global__ __launch_bounds__(256) void prep_kernel(const float* __restrict__ qw,
                                                   const float* __restrict__ kw,
                                                   const float* __restrict__ vw,
                                                   const float* __restrict__ pw,
                                                   const float* __restrict__ qb,
                                                   const float* __restrict__ kb,
                                                   __bf16* __restrict__ wqk,
                                                   __bf16* __restrict__ wv,
                                                   __bf16* __restrict__ wp,
                                                   float* __restrict__ qkb) {
    int bi = blockIdx.x;
    int t = threadIdx.x;
    if (bi == 1024) {
        int i = t * 4;
#pragma unroll
        for (int e = 0; e < 4; ++e)
            qkb[i + e] = (i + e < 512) ? qb[i + e] : kb[i + e - 512];
        return;
    }
    const float* src;
    __bf16* dst;
    int blk = bi & 255;
    if (bi < 256)       { src = qw; dst = wqk; }
    else if (bi < 512)  { src = kw; dst = wqk + 262144; }
    else if (bi < 768)  { src = vw; dst = wv; }
    else                { src = pw; dst = wp; }
    int i = blk * 256 + t;
    float4 v = ((const float4*)src)[i];
    bf16x4 o;
    o[0] = (__bf16)v.x; o[1] = (__bf16)v.y; o[2] = (__bf16)v.z; o[3] = (__bf16)v.w;
    ((bf16x4*)dst)[i] = o;
}

// ------- softmax: one wave per row of 1024 bf16, in place, no LDS -------
__global__ __launch_bounds__(256) void softmax_bf16(__bf16* __restrict__ S) {
    int row = blockIdx.x * 4 + (threadIdx.x >> 6);
    int lane = threadIdx.x & 63;
    __bf16* p = S + (size_t)row * N_SP + lane * 16;
    bf16x8 v0 = *(bf16x8*)p;
    bf16x8 v1 = *(bf16x8*)(p + 8);
    float f[16];
#pragma unroll
    for (int e = 0; e < 8; ++e) { f[e] = (float)v0[e]; f[8 + e] = (float)v1[e]; }
    float m = f[0];
#pragma unroll
    for (int e = 1; e < 16; ++e) m = fmaxf(m, f[e]);
    for (int off = 32; off > 0; off >>= 1) m = fmaxf(m, __shfl_xor(m, off));
    float s = 0.f;
#pragma unroll
    for (int e = 0; e < 16; ++e) { f[e] = __expf(f[e] - m); s += f[e]; }
    for (int off = 32; off > 0; off >>= 1) s += __shfl_xor(s, off);
    float inv = 1.f / s;
#pragma unroll
    for (int e = 0; e < 8; ++e) { v0[e] = (__bf16)(f[e] * inv); v1[e] = (__bf16)(f[8 + e] * inv); }
    *(bf16x8*)p = v0;
    *(bf16x8*)(p + 8) = v1;
}

// ============ 128x128 8-wave GEMM, BK=64, dbuf, depth-1.5 prefetch ============
// (best measured config — r8, 247us)
// EPI: 0 bf16; 2 bf16+bias[row]; 4 f32+bias[row]+resid (resid prefetched tail);
//      5 bf16*scale; 6 bf16+bias[col] split cols<512 -> Y, >=512 -> Y2
#define WAITV(n) asm volatile("s_waitcnt vmcnt(" #n ")" ::: "memory")
#define BAR() __builtin_amdgcn_s_barrier()

template <int M, int N, int K, int LDA, int LDB, int EPI>
__global__ __launch_bounds__(512, 4) void gemmP(const __bf16* __restrict__ A, size_t sA,
                                                const __bf16* __restrict__ BT, size_t sB,
                                                void* __restrict__ Y, size_t sY,
                                                const float* __restrict__ bias,
                                                const float* __restrict__ resid, size_t sR,
                                                float scale, void* __restrict__ Y2) {
    static_assert(M % 128 == 0 && N % 128 == 0 && K % 128 == 0, "shape");
    constexpr int GX = N / 128, GY = M / 128, NT = K / 64;
    __shared__ __align__(16) __bf16 lds[2][2][8192];   // [buf][A/B][128 rows x 64 k]

    const int tid = threadIdx.x;
    const int w = tid >> 6, lane = tid & 63;
    const int wm = w >> 1, wn = w & 1;                 // 4 x 2 wave grid, tile 32x64
    const int lrow = lane & 15, koct = lane >> 4;

    const int nwg = gridDim.x;
    const int wg = ((int)blockIdx.x & 7) * (nwg >> 3) + ((int)blockIdx.x >> 3);
    const int bz = wg / (GX * GY);
    const int rem = wg - bz * (GX * GY);
    const int bm = (rem / GX) * 128, bn = (rem % GX) * 128;

    const __bf16* Ab = A + (size_t)bz * sA;
    const __bf16* Bb = BT + (size_t)bz * sB;

    const int srow = tid >> 3;
    const int kswz = ((tid & 7) ^ (srow & 7)) * 8;
    const __bf16* srcA = Ab + (size_t)(bm + srow) * LDA + kswz;
    const __bf16* srcB = Bb + (size_t)(bn + srow) * LDB + kswz;

#define STG(buf, kt) do { \
    gload16(srcA + (size_t)(kt) * 64,                      &lds[buf][0][w * 512]); \
    gload16(srcA + (size_t)64 * LDA + (size_t)(kt) * 64,   &lds[buf][0][4096 + w * 512]); \
    gload16(srcB + (size_t)(kt) * 64,                      &lds[buf][1][w * 512]); \
    gload16(srcB + (size_t)64 * LDB + (size_t)(kt) * 64,   &lds[buf][1][4096 + w * 512]); \
} while (0)

    const int ks0 = (koct ^ (lrow & 7)) * 8;
    const int ks1 = ks0 ^ 32;
    const int aoff = (wm * 32 + lrow) * 64;
    const int boff = (wn * 64 + lrow) * 64;

    bf16x8 aF[2][2], bF[4][2];
    f32x4 acc[2][4];
#pragma unroll
    for (int i = 0; i < 2; ++i)
#pragma unroll
        for (int j = 0; j < 4; ++j) acc[i][j] = (f32x4){0.f, 0.f, 0.f, 0.f};

    const float* Rb = (EPI == 4) ? (resid + (size_t)bz * sR) : nullptr;
    float xr[2][4][4];   // EPI==4 residual prefetch (DCE'd otherwise)

#define RD_ALL(ct) do { \
    _Pragma("unroll") for (int i = 0; i < 2; ++i) { \
        aF[i][0] = *(const bf16x8*)&lds[ct][0][aoff + i * 1024 + ks0]; \
        aF[i][1] = *(const bf16x8*)&lds[ct][0][aoff + i * 1024 + ks1]; } \
    _Pragma("unroll") for (int j = 0; j < 4; ++j) { \
        bF[j][0] = *(const bf16x8*)&lds[ct][1][boff + j * 1024 + ks0]; \
        bF[j][1] = *(const bf16x8*)&lds[ct][1][boff + j * 1024 + ks1]; } \
} while (0)

#define MM8(KS) do { \
    __builtin_amdgcn_s_setprio(1); \
    _Pragma("unroll") for (int i = 0; i < 2; ++i) \
    _Pragma("unroll") for (int j = 0; j < 4; ++j) \
        acc[i][j] = __builtin_amdgcn_mfma_f32_16x16x32_bf16( \
            aF[i][KS], bF[j][KS], acc[i][j], 0, 0, 0); \
    __builtin_amdgcn_s_setprio(0); \
} while (0)

    STG(0, 0);
    STG(1, 1);

#pragma unroll 1
    for (int t = 0; t < NT; ++t) {
        const int c = t & 1;
        if (t < NT - 1) { WAITV(4); } else { WAITV(0); }
        BAR();
        if constexpr (EPI == 4) {
            if (t == NT - 1) {     // residual prefetch flies under tail MFMAs
#pragma unroll
                for (int i = 0; i < 2; ++i)
#pragma unroll
                    for (int r = 0; r < 4; ++r)
#pragma unroll
                        for (int j = 0; j < 4; ++j)
                            xr[i][r][j] = Rb[(size_t)(bm + wm * 32 + i * 16 + koct * 4 + r) * N
                                             + bn + wn * 64 + j * 16 + lrow];
            }
        }
        RD_ALL(c);
        MM8(0);
        asm volatile("s_waitcnt lgkmcnt(0)" ::: "memory");
        __builtin_amdgcn_sched_barrier(0);
        BAR();
        if (t + 2 < NT) STG(c, t + 2);
        MM8(1);
    }

    // epilogue: C/D layout col=lane&15, row=koct*4+reg
    float* Yf = (float*)Y + (size_t)bz * sY;
    __bf16* Yh = (__bf16*)Y + (size_t)bz * sY;
    __bf16* Y6 = (EPI == 6) ? ((bn < 512) ? (__bf16*)Y : (__bf16*)Y2) : nullptr;
#pragma unroll
    for (int i = 0; i < 2; ++i)
#pragma unroll
        for (int r = 0; r < 4; ++r) {
            int grow = bm + wm * 32 + i * 16 + koct * 4 + r;
            float brv = (EPI == 2 || EPI == 4) ? bias[grow] : 0.f;
#pragma unroll
            for (int j = 0; j < 4; ++j) {
                int gcol = bn + wn * 64 + j * 16 + lrow;
                float vv = acc[i][j][r];
                if (EPI == 6) vv += bias[gcol];
                if (EPI == 2 || EPI == 4) vv += brv;
                if (EPI == 5) vv *= scale;
                if (EPI == 4) {
                    Yf[(size_t)grow * N + gcol] = vv + xr[i][r][j];
                } else if (EPI == 6) {
                    Y6[(size_t)grow * 512 + (gcol & 511)] = (__bf16)vv;
                } else {
                    Yh[(size_t)grow * N + gcol] = (__bf16)vv;
                }
            }
        }
#undef STG
#undef RD_ALL
#undef MM8
}

extern "C" void kernel_launch(void* const* d_in, const int* in_sizes, int n_in,
                              void* d_out, int out_size, void* d_ws, size_t ws_size,
                              hipStream_t stream) {
    const float* x      = (const float*)d_in[0];
    const float* norm_w = (const float*)d_in[1];
    const float* norm_b = (const float*)d_in[2];
    const float* q_w    = (const float*)d_in[3];
    const float* q_b    = (const float*)d_in[4];
    const float* k_w    = (const float*)d_in[5];
    const float* k_b    = (const float*)d_in[6];
    const float* v_w    = (const float*)d_in[7];
    const float* v_b    = (const float*)d_in[8];
    const float* proj_w = (const float*)d_in[9];
    const float* proj_b = (const float*)d_in[10];
    float* out = (float*)d_out;

    const size_t ELEM = (size_t)N_SP * C_DIM;            // 524288 elems = 1MB bf16
    const size_t QK   = (size_t)N_SP * N_SP;
    char* ws = (char*)d_ws;
    __bf16* hT  = (__bf16*)ws;                           // 32MB [b][n][c], reused as Ot
    __bf16* qT  = (__bf16*)(ws + ((size_t)32 << 20));    // 32MB [b][n][512]
    __bf16* kT  = (__bf16*)(ws + ((size_t)64 << 20));    // 32MB [b][n][512]
    __bf16* wqk = (__bf16*)(ws + ((size_t)96 << 20));    // 1MB [1024][512]
    __bf16* wv  = (__bf16*)(ws + ((size_t)97 << 20));    // 0.5MB
    __bf16* wp  = wv + 262144;                           // 0.5MB
    float* qkb  = (float*)(ws + ((size_t)98 << 20));     // 4KB
    size_t sbase = ((size_t)99 << 20);
    __bf16* S = (__bf16*)(ws + sbase);                   // chunk x [1024][1024] bf16
    __bf16* v  = (__bf16*)d_out;                         // V lives in d_out until proj
    __bf16* Ot = hT;

    int chunk = (int)((ws_size - sbase) >> 21);          // 2MB per batch of S
    if (chunk > B_DIM) chunk = B_DIM;
    if (chunk < 1) chunk = 1;

    gn_fused_kernel<<<B_DIM * GROUPS, 256, 0, stream>>>(x, norm_w, norm_b, hT);
    prep_kernel<<<1025, 256, 0, stream>>>(q_w, k_w, v_w, proj_w, q_b, k_b,
                                          wqk, wv, wp, qkb);

    // qT[n][oc] / kT[n][oc] = hT[n][:] x (wq||wk)^T + bias, split outputs
    gemmP<32768, 1024, 512, 512, 512, 6><<<2048, 512, 0, stream>>>(
        hT, 0, wqk, 0, qT, 0, qkb, nullptr, 0, 1.f, kT);
    // v[b][oc][n] = wv[oc][:] x hT[b][n][:] + v_b[oc]
    gemmP<512, 1024, 512, 512, 512, 2><<<1024, 512, 0, stream>>>(
        wv, 0, hT, ELEM, v, ELEM, v_b, nullptr, 0, 1.f, nullptr);

    const float scale = 0.044194173824159216f;  // 512^-0.5
    for (int b0 = 0; b0 < B_DIM; b0 += chunk) {
        int nb = (b0 + chunk <= B_DIM) ? chunk : (B_DIM - b0);
        // S[i][j] = bf16( scale * sum_c qT[i][c] kT[j][c] )
        gemmP<1024, 1024, 512, 512, 512, 5><<<64 * nb, 512, 0, stream>>>(
            qT + (size_t)b0 * ELEM, ELEM, kT + (size_t)b0 * ELEM, ELEM,
            S, QK, nullptr, nullptr, 0, scale, nullptr);
        softmax_bf16<<<nb * N_SP / 4, 256, 0, stream>>>(S);
        // Ot[i][c] = sum_j P[i][j] v[c][j]
        gemmP<1024, 512, 1024, 1024, 1024, 0><<<32 * nb, 512, 0, stream>>>(
            S, QK, v + (size_t)b0 * ELEM, ELEM,
            Ot + (size_t)b0 * ELEM, ELEM, nullptr, nullptr, 0, 1.f, nullptr);
    }

    // out[b][oc][n] = wp[oc][:] x Ot[b][n][:] + proj_b[oc] + x[b][oc][n]
    gemmP<512, 1024, 512, 512, 512, 4><<<1024, 512, 0, stream>>>(
        wp, 0, Ot, ELEM, out, ELEM, proj_b, x, ELEM, 1.f, nullptr);
}